// Round 11
// baseline (209.541 us; speedup 1.0000x reference)
//
#include <hip/hip_runtime.h>

// out[b,a,c,k] = exp(-2*pi^2*(e_a-e_c)^2) * cos(2*pi*(m_a-m_c)) + diag noise
// R9 = R7 with the nontemporal store fixed: clang native vector type
// (ext_vector_type) instead of HIP_vector_type float4.
//  - block = 384 threads (384 % 3 == 0): channel pattern per thread is
//    loop-invariant -> selected ONCE into registers.
//  - diagonal written exactly (1 + nz_k) by a tiny second kernel.

static constexpr float KNEG2 = -28.4776592f; // -2*pi^2 * log2(e)

typedef float f32x4 __attribute__((ext_vector_type(4)));

__device__ __forceinline__ float sel3(float p0, float p1, float p2, int k) {
    float r = (k == 1) ? p1 : p0;
    return (k == 2) ? p2 : r;
}

__global__ __launch_bounds__(384) void smk_flat(
    const float* __restrict__ xc,      // (nb*n, 3)
    const float* __restrict__ mu,      // (3,)
    const float* __restrict__ inv_std, // (3,)
    float* __restrict__ out,           // (nb*n, n*3)
    int n)
{
    const int blk = blockIdx.x;        // b*n + a
    const int b   = blk / n;
    const int a   = blk - b * n;
    const int rb  = b * n;

    const float is0 = inv_std[0], is1 = inv_std[1], is2 = inv_std[2];
    const float mu0 = mu[0],      mu1 = mu[1],      mu2 = mu[2];

    const float* xa = xc + (size_t)(rb + a) * 3;
    const float ea0 = xa[0] * is0, ea1 = xa[1] * is1, ea2 = xa[2] * is2;
    const float ma0 = xa[0] * mu0, ma1 = xa[1] * mu1, ma2 = xa[2] * mu2;

    // per-thread static channel pattern: element j of this thread's float4
    // always has channel (k0 + j) % 3
    const int k0 = threadIdx.x % 3;
    float isP[4], muP[4], eaP[4], maP[4];
    #pragma unroll
    for (int j = 0; j < 4; ++j) {
        int kj = k0 + j; kj = (kj >= 3) ? kj - 3 : kj; kj = (kj >= 3) ? kj - 3 : kj;
        isP[j] = sel3(is0, is1, is2, kj);
        muP[j] = sel3(mu0, mu1, mu2, kj);
        eaP[j] = sel3(ea0, ea1, ea2, kj);
        maP[j] = sel3(ma0, ma1, ma2, kj);
    }

    const f32x4* __restrict__ xrow4 = reinterpret_cast<const f32x4*>(xc + (size_t)rb * 3);
    f32x4*       __restrict__ orow4 = reinterpret_cast<f32x4*>(out + (size_t)blk * 3 * n);

    const int nq = (3 * n) >> 2;       // float4s per row (1536 @ n=2048)
    #pragma unroll 4
    for (int idx = threadIdx.x; idx < nq; idx += 384) {
        const f32x4 xq = xrow4[idx];
        f32x4 r;
        #pragma unroll
        for (int j = 0; j < 4; ++j) {
            const float x  = xq[j];
            const float t  = __builtin_fmaf(-isP[j], x, eaP[j]);
            const float ex = __builtin_amdgcn_exp2f(t * t * KNEG2);
            const float u  = __builtin_fmaf(-muP[j], x, maP[j]);
            const float cs = __builtin_amdgcn_cosf(__builtin_amdgcn_fractf(u));
            r[j] = ex * cs;
        }
        __builtin_nontemporal_store(r, &orow4[idx]);
    }
}

__global__ __launch_bounds__(256) void smk_diag(
    const float* __restrict__ likerr, float* __restrict__ out, int n, int nbn)
{
    const int i = blockIdx.x * 256 + threadIdx.x;  // i = b*n + a
    if (i >= nbn) return;
    const int a = i % n;
    const float l0 = fminf(fmaxf(likerr[0], 0.1f), 1.0f);
    const float l1 = fminf(fmaxf(likerr[1], 0.1f), 1.0f);
    const float l2 = fminf(fmaxf(likerr[2], 0.1f), 1.0f);
    float* p = out + (size_t)i * 3 * n + 3 * a;
    p[0] = 1.0f + 1e-4f + l0 * l0;
    p[1] = 1.0f + 1e-4f + l1 * l1;
    p[2] = 1.0f + 1e-4f + l2 * l2;
}

// Fallback (R4 structure, diag in-kernel) for shapes with n % 512 != 0
__global__ __launch_bounds__(256) void smk_main(
    const float* __restrict__ xc, const float* __restrict__ mu,
    const float* __restrict__ inv_std, const float* __restrict__ likerr,
    float* __restrict__ out, int n)
{
    const int blk = blockIdx.x;
    const int b   = blk / n;
    const int a   = blk - b * n;
    const int rb  = b * n;

    const float is0 = inv_std[0], is1 = inv_std[1], is2 = inv_std[2];
    const float mu0 = mu[0],      mu1 = mu[1],      mu2 = mu[2];

    const float* xa = xc + (size_t)(rb + a) * 3;
    const float ea0 = xa[0] * is0, ea1 = xa[1] * is1, ea2 = xa[2] * is2;
    const float ma0 = xa[0] * mu0, ma1 = xa[1] * mu1, ma2 = xa[2] * mu2;

    const float l0 = fminf(fmaxf(likerr[0], 0.1f), 1.0f);
    const float l1 = fminf(fmaxf(likerr[1], 0.1f), 1.0f);
    const float l2 = fminf(fmaxf(likerr[2], 0.1f), 1.0f);
    const float nz0 = 1e-4f + l0 * l0;
    const float nz1 = 1e-4f + l1 * l1;
    const float nz2 = 1e-4f + l2 * l2;

    const float* __restrict__ xrow = xc  + (size_t)rb  * 3;
    float*       __restrict__ orow = out + (size_t)blk * 3 * n;

    #pragma unroll 4
    for (int c = threadIdx.x; c < n; c += 256) {
        const float3 xq = *reinterpret_cast<const float3*>(xrow + 3 * c);
        float t0 = ea0 - xq.x * is0, u0 = ma0 - xq.x * mu0;
        float t1 = ea1 - xq.y * is1, u1 = ma1 - xq.y * mu1;
        float t2 = ea2 - xq.z * is2, u2 = ma2 - xq.z * mu2;
        float r0 = __builtin_amdgcn_exp2f(t0 * t0 * KNEG2) *
                   __builtin_amdgcn_cosf(__builtin_amdgcn_fractf(u0));
        float r1 = __builtin_amdgcn_exp2f(t1 * t1 * KNEG2) *
                   __builtin_amdgcn_cosf(__builtin_amdgcn_fractf(u1));
        float r2 = __builtin_amdgcn_exp2f(t2 * t2 * KNEG2) *
                   __builtin_amdgcn_cosf(__builtin_amdgcn_fractf(u2));
        if (c == a) { r0 += nz0; r1 += nz1; r2 += nz2; }
        *reinterpret_cast<float3*>(orow + 3 * c) = make_float3(r0, r1, r2);
    }
}

extern "C" void kernel_launch(void* const* d_in, const int* in_sizes, int n_in,
                              void* d_out, int out_size, void* d_ws, size_t ws_size,
                              hipStream_t stream) {
    const float* xc      = (const float*)d_in[0];
    const float* mu      = (const float*)d_in[1];
    const float* inv_std = (const float*)d_in[2];
    const float* likerr  = (const float*)d_in[3];
    float*       out     = (float*)d_out;

    const int  C = in_sizes[3];                       // nchannel = 3
    const int  D = in_sizes[1] / C;                   // ndim = 1
    const long P = (long)in_sizes[0] / ((long)C * D); // nb*n
    const long n = (long)out_size / (P * C);          // n
    (void)n_in; (void)d_ws; (void)ws_size;

    if (n % 512 == 0) {
        smk_flat<<<dim3((unsigned)P), dim3(384), 0, stream>>>(
            xc, mu, inv_std, out, (int)n);
        smk_diag<<<dim3((unsigned)((P + 255) / 256)), dim3(256), 0, stream>>>(
            likerr, out, (int)n, (int)P);
    } else {
        smk_main<<<dim3((unsigned)P), dim3(256), 0, stream>>>(
            xc, mu, inv_std, likerr, out, (int)n);
    }
}